// Round 1
// baseline (291.136 us; speedup 1.0000x reference)
//
#include <hip/hip_runtime.h>
#include <hip/hip_bf16.h>
#include <math.h>

#define KC 32
#define DC 128
#define QC 16
#define NPTS 20000

// ws layout (floats)
#define WS_INVPSI 0            // 128
#define WS_W      128          // 32*128 = 4096
#define WS_V      4224         // 32*16  = 512
#define WS_MINV   4736         // 32*256 = 8192
#define WS_C2     12928        // 32
// total 12960 floats = 51840 bytes

// ---------------------------------------------------------------------------
// Kernel 1: per-component precompute. One block per component k.
//   M = I + Lam^T diag(invpsi) Lam  (16x16), Cholesky -> Minv, logdetM
//   w_k = invpsi * mu_k ; v_k = (Lam*invpsi)^T mu_k ; t_k = w_k . mu_k
//   C2_k = log_pi_k - 0.5*(D*log2pi + sum log psi' + logdetM) - 0.5*t_k
// ---------------------------------------------------------------------------
__global__ __launch_bounds__(256) void mfa_pre(
    const float* __restrict__ log_pi, const float* __restrict__ mu,
    const float* __restrict__ Lam, const float* __restrict__ log_psi,
    float* __restrict__ ws)
{
    int k = blockIdx.x;
    int t = threadIdx.x;
    __shared__ __align__(16) float invpsiS[DC];
    __shared__ float logpsiS[DC], muS[DC], wS[DC];
    __shared__ float lamR[DC*QC], lamSc[DC*QC];
    __shared__ float MS[QC*QC], LS[QC*QC], LinvS[QC*QC];

    if (t < DC) {
        float psi = expf(log_psi[t]) + 1e-5f + 1e-4f;   // psi + jitter
        invpsiS[t] = 1.0f / psi;
        logpsiS[t] = logf(psi);
        muS[t] = mu[k*DC + t];
    }
    __syncthreads();
    for (int e = t; e < DC*QC; e += 256) {
        float lv = Lam[k*DC*QC + e];
        lamR[e]  = lv;
        lamSc[e] = lv * invpsiS[e >> 4];
    }
    __syncthreads();
    {   // M[q][r]
        int q = t >> 4, r = t & 15;
        float s = (q == r) ? 1.0f : 0.0f;
        for (int d = 0; d < DC; d++) s += lamSc[d*QC + q] * lamR[d*QC + r];
        MS[q*QC + r] = s;
    }
    __syncthreads();
    // Cholesky (lower) of MS into LS
    for (int j = 0; j < QC; j++) {
        if (t == 0) {
            float s = MS[j*QC + j];
            for (int x = 0; x < j; x++) s -= LS[j*QC + x] * LS[j*QC + x];
            LS[j*QC + j] = sqrtf(s);
        }
        __syncthreads();
        if (t > j && t < QC) {
            float s = MS[t*QC + j];
            for (int x = 0; x < j; x++) s -= LS[t*QC + x] * LS[j*QC + x];
            LS[t*QC + j] = s / LS[j*QC + j];
        }
        __syncthreads();
    }
    // Linv (lower triangular inverse of LS); thread t owns column t
    if (t < QC) {
        for (int i = 0; i < QC; i++) {
            if (i < t) { LinvS[i*QC + t] = 0.0f; continue; }
            float s = (i == t) ? 1.0f : 0.0f;
            for (int x = t; x < i; x++) s -= LS[i*QC + x] * LinvS[x*QC + t];
            LinvS[i*QC + t] = s / LS[i*QC + i];
        }
    }
    __syncthreads();
    {   // Minv = Linv^T Linv
        int q = t >> 4, r = t & 15;
        float s = 0.0f;
        for (int x = 0; x < QC; x++) s += LinvS[x*QC + q] * LinvS[x*QC + r];
        ws[WS_MINV + k*QC*QC + q*QC + r] = s;
    }
    if (t < DC) {
        float wv = invpsiS[t] * muS[t];
        wS[t] = wv;
        ws[WS_W + k*DC + t] = wv;
    }
    __syncthreads();
    if (t < QC) {
        float s = 0.0f;
        for (int d = 0; d < DC; d++) s += lamSc[d*QC + t] * muS[d];
        ws[WS_V + k*QC + t] = s;
    }
    if (t == 0) {
        float logdetM = 0.0f;
        for (int j = 0; j < QC; j++) logdetM += 2.0f * logf(LS[j*QC + j]);
        float slp = 0.0f;
        for (int d = 0; d < DC; d++) slp += logpsiS[d];
        float tv = 0.0f;
        for (int d = 0; d < DC; d++) tv += wS[d] * muS[d];
        const float log2pi = 1.8378770664093453f;
        ws[WS_C2 + k] = log_pi[k] - 0.5f*((float)DC*log2pi + slp + logdetM) - 0.5f*tv;
    }
    if (k == 0 && t < DC) ws[WS_INVPSI + t] = invpsiS[t];
}

// ---------------------------------------------------------------------------
// Kernel 2: main. Block = 256 threads = 256 samples; 4 components per block.
// Grid (79, 8). lr[n,k] = C2_k + w_k.x - 0.5*s2(x) + 0.5*u^T Minv u,
// u = (Lam*invpsi)^T x - v_k. Writes unnormalized lr to out[n*32+k].
// ---------------------------------------------------------------------------
__global__ __launch_bounds__(256, 2) void mfa_main(
    const float* __restrict__ X, const float* __restrict__ Lam,
    const float* __restrict__ ws, float* __restrict__ out)
{
    __shared__ __align__(16) float invpsiS[DC];
    __shared__ __align__(16) float lamS[DC*20];      // [d][0..15]=Lam*invpsi, [d][16]=w
    __shared__ __align__(16) float minvS[4*QC*QC];
    __shared__ float vS[QC];
    __shared__ float c2S;

    int t = threadIdx.x;
    int n = blockIdx.x * 256 + t;
    int k0 = blockIdx.y * 4;

    if (t < DC) invpsiS[t] = ws[WS_INVPSI + t];
    {   // stage 4 Minv matrices (1024 floats) once
        const float4* src = (const float4*)(ws + WS_MINV + k0*QC*QC);
        ((float4*)minvS)[t] = src[t];
    }
    __syncthreads();

    bool valid = (n < NPTS);
    const float4* Xp = (const float4*)(X + (size_t)(valid ? n : 0) * DC);
    float4 xr[32];
    float s2 = 0.0f;
#pragma unroll
    for (int i = 0; i < 32; i++) {
        xr[i] = Xp[i];
        float4 ip = ((const float4*)invpsiS)[i];
        s2 += xr[i].x*xr[i].x*ip.x + xr[i].y*xr[i].y*ip.y
            + xr[i].z*xr[i].z*ip.z + xr[i].w*xr[i].w*ip.w;
    }

    float lr[4];
#pragma unroll 1
    for (int kk = 0; kk < 4; kk++) {
        int k = k0 + kk;
        __syncthreads();
        for (int e = t; e < DC*QC; e += 256) {
            int d = e >> 4, q = e & 15;
            lamS[d*20 + q] = Lam[k*DC*QC + e] * invpsiS[d];
        }
        if (t < DC) lamS[t*20 + 16] = ws[WS_W + k*DC + t];
        if (t < QC) vS[t] = ws[WS_V + k*QC + t];
        if (t == QC) c2S = ws[WS_C2 + k];
        __syncthreads();

        float u[16];
#pragma unroll
        for (int q = 0; q < 16; q++) u[q] = 0.0f;
        float p = 0.0f;
#pragma unroll
        for (int i = 0; i < 32; i++) {
            float4 xv = xr[i];
#pragma unroll
            for (int j = 0; j < 4; j++) {
                int d = i*4 + j;
                float xd = (j == 0) ? xv.x : (j == 1) ? xv.y : (j == 2) ? xv.z : xv.w;
                const float4* l4 = (const float4*)(lamS + d*20);
                float4 a = l4[0], b = l4[1], c = l4[2], e4 = l4[3];
                u[0]  += a.x*xd;  u[1]  += a.y*xd;  u[2]  += a.z*xd;  u[3]  += a.w*xd;
                u[4]  += b.x*xd;  u[5]  += b.y*xd;  u[6]  += b.z*xd;  u[7]  += b.w*xd;
                u[8]  += c.x*xd;  u[9]  += c.y*xd;  u[10] += c.z*xd;  u[11] += c.w*xd;
                u[12] += e4.x*xd; u[13] += e4.y*xd; u[14] += e4.z*xd; u[15] += e4.w*xd;
                p += lamS[d*20 + 16] * xd;
            }
        }
#pragma unroll
        for (int q = 0; q < 16; q++) u[q] -= vS[q];
        float quad = 0.0f;
#pragma unroll
        for (int q = 0; q < 16; q++) {
            float uq = u[q];
            const float4* m4 = (const float4*)(minvS + kk*QC*QC + q*QC);
            float4 m0 = m4[0], m1 = m4[1], m2 = m4[2], m3 = m4[3];
            quad += uq*(m0.x*u[0] + m0.y*u[1] + m0.z*u[2] + m0.w*u[3]
                      + m1.x*u[4] + m1.y*u[5] + m1.z*u[6] + m1.w*u[7]
                      + m2.x*u[8] + m2.y*u[9] + m2.z*u[10] + m2.w*u[11]
                      + m3.x*u[12] + m3.y*u[13] + m3.z*u[14] + m3.w*u[15]);
        }
        lr[kk] = c2S + p - 0.5f*s2 + 0.5f*quad;
    }

    if (valid) {
#pragma unroll
        for (int kk = 0; kk < 4; kk++) out[(size_t)n*KC + k0 + kk] = lr[kk];
    }
}

// ---------------------------------------------------------------------------
// Kernel 3: in-place logsumexp normalize + log-likelihood output.
// ---------------------------------------------------------------------------
__global__ __launch_bounds__(256) void mfa_norm(float* __restrict__ out)
{
    int n = blockIdx.x * 256 + threadIdx.x;
    if (n >= NPTS) return;
    float lr[KC];
    float m = -1e30f;
#pragma unroll
    for (int k = 0; k < KC; k++) {
        lr[k] = out[(size_t)n*KC + k];
        m = fmaxf(m, lr[k]);
    }
    float s = 0.0f;
#pragma unroll
    for (int k = 0; k < KC; k++) s += expf(lr[k] - m);
    float ll = m + logf(s);
#pragma unroll
    for (int k = 0; k < KC; k++) out[(size_t)n*KC + k] = lr[k] - ll;
    out[(size_t)NPTS*KC + n] = ll;
}

extern "C" void kernel_launch(void* const* d_in, const int* in_sizes, int n_in,
                              void* d_out, int out_size, void* d_ws, size_t ws_size,
                              hipStream_t stream)
{
    const float* X       = (const float*)d_in[0];
    const float* log_pi  = (const float*)d_in[1];
    const float* mu      = (const float*)d_in[2];
    const float* Lam     = (const float*)d_in[3];
    const float* log_psi = (const float*)d_in[4];
    float* out = (float*)d_out;
    float* ws  = (float*)d_ws;

    hipLaunchKernelGGL(mfa_pre, dim3(KC), dim3(256), 0, stream,
                       log_pi, mu, Lam, log_psi, ws);
    hipLaunchKernelGGL(mfa_main, dim3(79, 8), dim3(256), 0, stream,
                       X, Lam, ws, out);
    hipLaunchKernelGGL(mfa_norm, dim3(79), dim3(256), 0, stream, out);
}

// Round 2
// 64.875 us; speedup vs baseline: 4.4876x; 4.4876x over previous
//
#include <hip/hip_runtime.h>
#include <hip/hip_bf16.h>
#include <math.h>

#define KC 32
#define DC 128
#define QC 16
#define NPTS 20000

// ws layout:
//   float  invpsi[128]    @ float ofs 0
//   float  C2p[32]        @ float ofs 128
//   short  BT_HI[544*128] @ byte ofs 640
//   short  BT_LO[544*128] @ byte ofs 640+139264=139904
// total 279168 bytes
#define WS_INVPSI_F 0
#define WS_C2P_F    128
#define WS_BTHI_B   640
#define WS_BTLO_B   139904

typedef __attribute__((ext_vector_type(8))) short bf16x8;
typedef __attribute__((ext_vector_type(4))) float f32x4;

static __device__ __forceinline__ short f2bf(float x) {
    union { float f; unsigned u; } v; v.f = x;
    unsigned r = v.u + 0x7fffu + ((v.u >> 16) & 1u);
    return (short)(r >> 16);
}
static __device__ __forceinline__ float bf2f(short h) {
    union { unsigned u; float f; } v; v.u = ((unsigned)(unsigned short)h) << 16;
    return v.f;
}

// ---------------------------------------------------------------------------
// Kernel 1: per-component precompute. One block per component k.
// Computes M = I + B^T Lam (B = Lam*invpsi), chol L, Linv, then
//   G_k = Linv B^T  (16x128), h_k = Linv v_k, w'_k = invpsi*mu - G^T h,
//   C2'_k = log_pi -0.5(D log2pi + sum log psi' + logdetM + mu^T Psi^-1 mu)
//           + 0.5 ||h||^2
// Emits bf16 hi/lo of rows of B-matrix: rows k*16+q = G_k[q][:],
// row 512+k = w'_k. Also invpsi (block 0) and C2'.
// ---------------------------------------------------------------------------
__global__ __launch_bounds__(256) void mfa_pre(
    const float* __restrict__ log_pi, const float* __restrict__ mu,
    const float* __restrict__ Lam, const float* __restrict__ log_psi,
    float* __restrict__ wsf, short* __restrict__ btH, short* __restrict__ btL)
{
    int k = blockIdx.x;
    int t = threadIdx.x;
    __shared__ float invpsiS[DC], logpsiS[DC], muS[DC];
    __shared__ float lamR[DC*QC], lamSc[DC*QC];
    __shared__ float MS[QC*QC], LS[QC*QC], LinvS[QC*QC];
    __shared__ float GS[QC*DC];      // [q][d]
    __shared__ float vS[QC], hS[QC];

    if (t < DC) {
        float psi = expf(log_psi[t]) + 1e-5f + 1e-4f;
        invpsiS[t] = 1.0f / psi;
        logpsiS[t] = logf(psi);
        muS[t] = mu[k*DC + t];
    }
    __syncthreads();
    for (int e = t; e < DC*QC; e += 256) {
        float lv = Lam[k*DC*QC + e];
        lamR[e]  = lv;
        lamSc[e] = lv * invpsiS[e >> 4];
    }
    __syncthreads();
    {   // M[q][r] = I + B^T Lam
        int q = t >> 4, r = t & 15;
        float s = (q == r) ? 1.0f : 0.0f;
        for (int d = 0; d < DC; d++) s += lamSc[d*QC + q] * lamR[d*QC + r];
        MS[q*QC + r] = s;
    }
    __syncthreads();
    // Cholesky (lower) of MS into LS
    for (int j = 0; j < QC; j++) {
        if (t == 0) {
            float s = MS[j*QC + j];
            for (int x = 0; x < j; x++) s -= LS[j*QC + x] * LS[j*QC + x];
            LS[j*QC + j] = sqrtf(s);
        }
        __syncthreads();
        if (t > j && t < QC) {
            float s = MS[t*QC + j];
            for (int x = 0; x < j; x++) s -= LS[t*QC + x] * LS[j*QC + x];
            LS[t*QC + j] = s / LS[j*QC + j];
        }
        __syncthreads();
    }
    // Linv, thread t owns column t (full matrix, zeros above diagonal)
    if (t < QC) {
        for (int i = 0; i < QC; i++) {
            if (i < t) { LinvS[i*QC + t] = 0.0f; continue; }
            float s = (i == t) ? 1.0f : 0.0f;
            for (int x = t; x < i; x++) s -= LS[i*QC + x] * LinvS[x*QC + t];
            LinvS[i*QC + t] = s / LS[i*QC + i];
        }
    }
    __syncthreads();
    if (t < QC) {       // v = B^T mu
        float s = 0.0f;
        for (int d = 0; d < DC; d++) s += lamSc[d*QC + t] * muS[d];
        vS[t] = s;
    }
    __syncthreads();
    if (t < QC) {       // h = Linv v
        float s = 0.0f;
        for (int x = 0; x <= t; x++) s += LinvS[t*QC + x] * vS[x];
        hS[t] = s;
    }
    // G[q][d] = sum_{x<=q} Linv[q][x] * Bsc[d][x]
    for (int e = t; e < QC*DC; e += 256) {
        int q = e >> 7, d = e & 127;
        float s = 0.0f;
        for (int x = 0; x <= q; x++) s += LinvS[q*QC + x] * lamSc[d*QC + x];
        GS[e] = s;
    }
    __syncthreads();
    // emit G rows as bf16 hi/lo
    for (int e = t; e < QC*DC; e += 256) {
        int q = e >> 7, d = e & 127;
        float g = GS[e];
        short hi = f2bf(g);
        short lo = f2bf(g - bf2f(hi));
        btH[(k*QC + q)*DC + d] = hi;
        btL[(k*QC + q)*DC + d] = lo;
    }
    // w' row
    if (t < DC) {
        float gh = 0.0f;
        for (int q = 0; q < QC; q++) gh += GS[q*DC + t] * hS[q];
        float wp = invpsiS[t]*muS[t] - gh;
        short hi = f2bf(wp);
        short lo = f2bf(wp - bf2f(hi));
        btH[(512 + k)*DC + t] = hi;
        btL[(512 + k)*DC + t] = lo;
    }
    if (t == 0) {
        float logdetM = 0.0f;
        for (int j = 0; j < QC; j++) logdetM += 2.0f * logf(LS[j*QC + j]);
        float slp = 0.0f, tv = 0.0f, hh = 0.0f;
        for (int d = 0; d < DC; d++) slp += logpsiS[d];
        for (int d = 0; d < DC; d++) tv += invpsiS[d]*muS[d]*muS[d];
        for (int q = 0; q < QC; q++) hh += hS[q]*hS[q];
        const float log2pi = 1.8378770664093453f;
        wsf[WS_C2P_F + k] = log_pi[k]
            - 0.5f*((float)DC*log2pi + slp + logdetM + tv) + 0.5f*hh;
    }
    if (k == 0 && t < DC) wsf[WS_INVPSI_F + t] = invpsiS[t];
}

// ---------------------------------------------------------------------------
// Kernel 2: fused MFMA GEMM + epilogue.
// grid (313, 8); block 256 = 4 waves x 16 samples. y-block owns 4 components:
// LDS rows 0..63 = G rows (4 tiles), 64..67 = w' rows, 68..79 = zero pad.
// Per wave: 5 N-tiles x 4 k-steps x 3 bf16-split MFMAs; epilogue squares the
// G-tile accs, shuffle-reduces over q, pulls p from the w'-tile acc and s2
// from register reduction, writes lr[n,k] directly to out.
// ---------------------------------------------------------------------------
__global__ __launch_bounds__(256) void mfa_gemm(
    const float* __restrict__ X, const float* __restrict__ wsf,
    const short* __restrict__ btH, const short* __restrict__ btL,
    float* __restrict__ out)
{
    __shared__ __align__(16) short ldsH[80*136];
    __shared__ __align__(16) short ldsL[80*136];

    int t = threadIdx.x;
    int yb = blockIdx.y;

    // stage B chunk (hi/lo), 80 rows x 128 cols, row stride 136 (2-way alias = free)
    for (int s = t; s < 80*16; s += 256) {
        int row = s >> 4, seg = s & 15;
        bf16x8 zh, zl;
#pragma unroll
        for (int j = 0; j < 8; j++) { zh[j] = 0; zl[j] = 0; }
        if (row < 68) {
            int gr = (row < 64) ? (yb*64 + row) : (512 + yb*4 + (row - 64));
            zh = *(const bf16x8*)(btH + gr*DC + seg*8);
            zl = *(const bf16x8*)(btL + gr*DC + seg*8);
        }
        *(bf16x8*)(ldsH + row*136 + seg*8) = zh;
        *(bf16x8*)(ldsL + row*136 + seg*8) = zl;
    }
    __syncthreads();

    int l  = t & 63, w = t >> 6;
    int m16 = l & 15, g4 = l >> 4;
    int rowbase = blockIdx.x*64 + w*16;
    int xrow = min(rowbase + m16, NPTS - 1);

    // load + convert A fragments (hi/lo), accumulate s2 partial
    bf16x8 aH[4], aL[4];
    float s2p = 0.0f;
#pragma unroll
    for (int ks = 0; ks < 4; ks++) {
        const float* xp = X + (size_t)xrow*DC + ks*32 + g4*8;
        const float* ip = wsf + WS_INVPSI_F + ks*32 + g4*8;
        float xs[8], is[8];
        *(float4*)&xs[0] = *(const float4*)xp;
        *(float4*)&xs[4] = *(const float4*)(xp + 4);
        *(float4*)&is[0] = *(const float4*)ip;
        *(float4*)&is[4] = *(const float4*)(ip + 4);
#pragma unroll
        for (int j = 0; j < 8; j++) {
            short hv = f2bf(xs[j]);
            aH[ks][j] = hv;
            aL[ks][j] = f2bf(xs[j] - bf2f(hv));
            s2p += xs[j]*xs[j]*is[j];
        }
    }
    s2p += __shfl_xor(s2p, 16, 64);
    s2p += __shfl_xor(s2p, 32, 64);   // full s2 for row m16, on every lane

    // w'-tile first (LDS rows 64..79): pacc[j] = p[row (g4*4+j)][k_local = l&15]
    f32x4 pacc = {0.f, 0.f, 0.f, 0.f};
#pragma unroll
    for (int ks = 0; ks < 4; ks++) {
        bf16x8 bh = *(const bf16x8*)(ldsH + (64 + m16)*136 + ks*32 + g4*8);
        bf16x8 bl = *(const bf16x8*)(ldsL + (64 + m16)*136 + ks*32 + g4*8);
        pacc = __builtin_amdgcn_mfma_f32_16x16x32_bf16(aH[ks], bh, pacc, 0, 0, 0);
        pacc = __builtin_amdgcn_mfma_f32_16x16x32_bf16(aL[ks], bh, pacc, 0, 0, 0);
        pacc = __builtin_amdgcn_mfma_f32_16x16x32_bf16(aH[ks], bl, pacc, 0, 0, 0);
    }

    // G tiles
#pragma unroll
    for (int nt = 0; nt < 4; nt++) {
        f32x4 acc = {0.f, 0.f, 0.f, 0.f};
#pragma unroll
        for (int ks = 0; ks < 4; ks++) {
            bf16x8 bh = *(const bf16x8*)(ldsH + (nt*16 + m16)*136 + ks*32 + g4*8);
            bf16x8 bl = *(const bf16x8*)(ldsL + (nt*16 + m16)*136 + ks*32 + g4*8);
            acc = __builtin_amdgcn_mfma_f32_16x16x32_bf16(aH[ks], bh, acc, 0, 0, 0);
            acc = __builtin_amdgcn_mfma_f32_16x16x32_bf16(aL[ks], bh, acc, 0, 0, 0);
            acc = __builtin_amdgcn_mfma_f32_16x16x32_bf16(aH[ks], bl, acc, 0, 0, 0);
        }
        int k = yb*4 + nt;
        float c2 = wsf[WS_C2P_F + k];
#pragma unroll
        for (int j = 0; j < 4; j++) {
            float v = acc[j]*acc[j];
            v += __shfl_xor(v, 1, 64);
            v += __shfl_xor(v, 2, 64);
            v += __shfl_xor(v, 4, 64);
            v += __shfl_xor(v, 8, 64);              // quad for row g4*4+j
            float pv  = __shfl(pacc[j], (l & 48) | nt, 64);
            float s2j = __shfl(s2p, g4*4 + j, 64);
            float lr = c2 + pv - 0.5f*s2j + 0.5f*v;
            int row = rowbase + g4*4 + j;
            if (m16 == 0 && row < NPTS) out[(size_t)row*KC + k] = lr;
        }
    }
}

// ---------------------------------------------------------------------------
// Kernel 3: in-place logsumexp normalize + log-likelihood output.
// ---------------------------------------------------------------------------
__global__ __launch_bounds__(256) void mfa_norm(float* __restrict__ out)
{
    int n = blockIdx.x * 256 + threadIdx.x;
    if (n >= NPTS) return;
    float lr[KC];
#pragma unroll
    for (int i = 0; i < 8; i++)
        *(float4*)&lr[i*4] = *(const float4*)(out + (size_t)n*KC + i*4);
    float m = -1e30f;
#pragma unroll
    for (int k = 0; k < KC; k++) m = fmaxf(m, lr[k]);
    float s = 0.0f;
#pragma unroll
    for (int k = 0; k < KC; k++) s += expf(lr[k] - m);
    float ll = m + logf(s);
#pragma unroll
    for (int k = 0; k < KC; k++) lr[k] -= ll;
#pragma unroll
    for (int i = 0; i < 8; i++)
        *(float4*)(out + (size_t)n*KC + i*4) = *(const float4*)&lr[i*4];
    out[(size_t)NPTS*KC + n] = ll;
}

extern "C" void kernel_launch(void* const* d_in, const int* in_sizes, int n_in,
                              void* d_out, int out_size, void* d_ws, size_t ws_size,
                              hipStream_t stream)
{
    const float* X       = (const float*)d_in[0];
    const float* log_pi  = (const float*)d_in[1];
    const float* mu      = (const float*)d_in[2];
    const float* Lam     = (const float*)d_in[3];
    const float* log_psi = (const float*)d_in[4];
    float* out = (float*)d_out;
    float* wsf = (float*)d_ws;
    short* btH = (short*)((char*)d_ws + WS_BTHI_B);
    short* btL = (short*)((char*)d_ws + WS_BTLO_B);

    hipLaunchKernelGGL(mfa_pre, dim3(KC), dim3(256), 0, stream,
                       log_pi, mu, Lam, log_psi, wsf, btH, btL);
    hipLaunchKernelGGL(mfa_gemm, dim3(313, 8), dim3(256), 0, stream,
                       X, wsf, btH, btL, out);
    hipLaunchKernelGGL(mfa_norm, dim3(79), dim3(256), 0, stream, out);
}

// Round 3
// 48.537 us; speedup vs baseline: 5.9982x; 1.3366x over previous
//
#include <hip/hip_runtime.h>
#include <hip/hip_bf16.h>
#include <math.h>

#define KC 32
#define DC 128
#define QC 16
#define NPTS 20000

// ws layout:
//   float  invpsi[128]    @ float ofs 0
//   float  C2p[32]        @ float ofs 128
//   short  BT_HI[544*128] @ byte ofs 640
//   short  BT_LO[544*128] @ byte ofs 640+139264=139904
// total 279168 bytes
#define WS_INVPSI_F 0
#define WS_C2P_F    128
#define WS_BTHI_B   640
#define WS_BTLO_B   139904

typedef __attribute__((ext_vector_type(8))) short bf16x8;
typedef __attribute__((ext_vector_type(4))) float f32x4;

// truncation-based bf16 hi/lo split helpers (hi = top 16 bits, lo = trunc(x - hi))
static __device__ __forceinline__ short bfhi(float x, float* hf) {
    unsigned bits = __float_as_uint(x);
    *hf = __uint_as_float(bits & 0xffff0000u);
    return (short)(bits >> 16);
}
static __device__ __forceinline__ short bftrunc(float x) {
    return (short)(__float_as_uint(x) >> 16);
}

// ---------------------------------------------------------------------------
// Kernel 1: per-component precompute, parallelized.
//   M = I + Lam^T diag(invpsi) Lam (16x16) via 256 threads
//   Cholesky of M via 16-lane shuffle (registers only)
//   G = Linv * (Lam*invpsi)^T via 128-thread forward solve (g in registers)
//   h = G mu; w' = invpsi*mu - G^T h; C2' constant; emit bf16 hi/lo rows.
// ---------------------------------------------------------------------------
__global__ __launch_bounds__(256) void mfa_pre(
    const float* __restrict__ log_pi, const float* __restrict__ mu,
    const float* __restrict__ Lam, const float* __restrict__ log_psi,
    float* __restrict__ wsf, short* __restrict__ btH, short* __restrict__ btL)
{
    int k = blockIdx.x, t = threadIdx.x;
    __shared__ float invpsiS[DC], muS[DC];
    __shared__ float lamR[DC*17];        // Lam[d][q] padded stride 17
    __shared__ float MS[QC*QC], LSm[QC*QC];
    __shared__ float invDS[QC];
    __shared__ float GT[QC*129];         // G[q][d] padded stride 129
    __shared__ float hS[QC];
    __shared__ float redS[4];
    __shared__ float hhS, ldS;

    float lp = 0.f, ipm = 0.f;
    if (t < DC) {
        float psi = expf(log_psi[t]) + 1e-5f + 1e-4f;
        float ip = 1.0f / psi;
        invpsiS[t] = ip;
        lp = logf(psi);
        float m = mu[k*DC + t];
        muS[t] = m;
        ipm = ip*m*m;
        if (k == 0) wsf[WS_INVPSI_F + t] = ip;
    }
    __syncthreads();
    for (int e = t; e < DC*QC; e += 256) {
        int d = e >> 4, q = e & 15;
        lamR[d*17 + q] = Lam[k*DC*QC + e];
    }
    __syncthreads();
    {   // M[q][r] = I + sum_d invpsi[d]*Lam[d][q]*Lam[d][r]
        int q = t >> 4, r = t & 15;
        float s = (q == r) ? 1.0f : 0.0f;
        for (int d = 0; d < DC; d++)
            s = fmaf(lamR[d*17 + q] * invpsiS[d], lamR[d*17 + r], s);
        MS[q*QC + r] = s;
    }
    __syncthreads();
    if (t < QC) {       // 16-lane shuffle Cholesky; lane i owns row i
        float m[QC], lrow[QC];
#pragma unroll
        for (int j = 0; j < QC; j++) m[j] = MS[t*QC + j];
#pragma unroll
        for (int j = 0; j < QC; j++) {
            float piv = __shfl(m[j], j, 16);
            float ljj = sqrtf(piv);
            float lij = m[j] / ljj;          // lane j gets exactly ljj
            lrow[j] = lij;
#pragma unroll
            for (int r = j + 1; r < QC; r++)
                m[r] = fmaf(-lij, __shfl(lij, r, 16), m[r]);
        }
#pragma unroll
        for (int j = 0; j < QC; j++) LSm[t*QC + j] = lrow[j];
        invDS[t] = 1.0f / lrow[t];
        float ld = 2.0f * logf(lrow[t]);
        ld += __shfl_xor(ld, 1, 16);
        ld += __shfl_xor(ld, 2, 16);
        ld += __shfl_xor(ld, 4, 16);
        ld += __shfl_xor(ld, 8, 16);
        if (t == 0) ldS = ld;
    }
    __syncthreads();
    float g[QC];
    if (t < DC) {       // forward solve L g = b, b = column t of (Lam*invpsi)^T
        float ip = invpsiS[t];
        float b[QC];
#pragma unroll
        for (int q = 0; q < QC; q++) b[q] = lamR[t*17 + q] * ip;
#pragma unroll
        for (int i = 0; i < QC; i++) {
            float s = b[i];
#pragma unroll
            for (int x = 0; x < i; x++)
                s = fmaf(-LSm[i*QC + x], g[x], s);   // broadcast LDS reads
            g[i] = s * invDS[i];
        }
#pragma unroll
        for (int q = 0; q < QC; q++) {
            GT[q*129 + t] = g[q];
            float hf;
            short hv = bfhi(g[q], &hf);
            btH[(k*QC + q)*DC + t] = hv;
            btL[(k*QC + q)*DC + t] = bftrunc(g[q] - hf);
        }
    }
    __syncthreads();
    if (t < QC) {       // h[q] = sum_d G[q][d] mu[d]; hh
        float s = 0.f;
        for (int d = 0; d < DC; d++)
            s = fmaf(GT[t*129 + d], muS[d], s);
        hS[t] = s;
        float hh = s*s;
        hh += __shfl_xor(hh, 1, 16);
        hh += __shfl_xor(hh, 2, 16);
        hh += __shfl_xor(hh, 4, 16);
        hh += __shfl_xor(hh, 8, 16);
        if (t == 0) hhS = hh;
    }
    {   // reduce slp, tv (nonzero only on t<128)
        float a = lp, b2 = ipm;
#pragma unroll
        for (int off = 1; off < 64; off <<= 1) {
            a  += __shfl_xor(a, off, 64);
            b2 += __shfl_xor(b2, off, 64);
        }
        if (t == 0)  { redS[0] = a; redS[1] = b2; }
        if (t == 64) { redS[2] = a; redS[3] = b2; }
    }
    __syncthreads();
    if (t < DC) {       // w' = invpsi*mu - G^T h
        float gh = 0.f;
#pragma unroll
        for (int q = 0; q < QC; q++) gh = fmaf(g[q], hS[q], gh);
        float wp = invpsiS[t]*muS[t] - gh;
        float hf;
        short hv = bfhi(wp, &hf);
        btH[(512 + k)*DC + t] = hv;
        btL[(512 + k)*DC + t] = bftrunc(wp - hf);
    }
    if (t == 0) {
        const float log2pi = 1.8378770664093453f;
        float slp = redS[0] + redS[2];
        float tv  = redS[1] + redS[3];
        wsf[WS_C2P_F + k] = log_pi[k]
            - 0.5f*((float)DC*log2pi + slp + ldS + tv) + 0.5f*hhS;
    }
}

// ---------------------------------------------------------------------------
// Kernel 2: fused MFMA GEMM + epilogue.
// grid (313, 8); block 256 = 4 waves x 16 samples; y-block owns 4 components.
// LDS: 68 rows (64 G + 4 w') x 128 bf16, hi+lo, XOR-swizzled (row&7)<<4,
// plus 3KB zeroed pad so the w'-tile's n=4..15 garbage reads stay in-bounds
// (those pacc columns are never extracted).
// ---------------------------------------------------------------------------
#define LROWS 68
#define LDS_H_BYTES (LROWS*256)      // 17408

__global__ __launch_bounds__(256, 4) void mfa_gemm(
    const float* __restrict__ X, const float* __restrict__ wsf,
    const short* __restrict__ btH, const short* __restrict__ btL,
    float* __restrict__ out)
{
    __shared__ __align__(16) char lds[2*LDS_H_BYTES + 12*256];   // 37888 B
    int t = threadIdx.x;
    int yb = blockIdx.y;

    // zero the pad (rows 68..79 of the L region, read by the w'-tile)
    {
        bf16x8 z;
#pragma unroll
        for (int j = 0; j < 8; j++) z[j] = 0;
        if (t < 12*16)
            *(bf16x8*)(lds + 2*LDS_H_BYTES + t*16) = z;
    }
    // stage B chunk hi/lo with XOR swizzle
    for (int s = t; s < LROWS*16; s += 256) {
        int row = s >> 4, seg = s & 15;
        int gr = (row < 64) ? (yb*64 + row) : (512 + yb*4 + (row - 64));
        unsigned bo = ((unsigned)(row*256 + seg*16)) ^ ((unsigned)(row & 7) << 4);
        *(bf16x8*)(lds + bo)               = *(const bf16x8*)(btH + gr*DC + seg*8);
        *(bf16x8*)(lds + LDS_H_BYTES + bo) = *(const bf16x8*)(btL + gr*DC + seg*8);
    }

    int l = t & 63, w = t >> 6;
    int m16 = l & 15, g4 = l >> 4;
    int rowbase = blockIdx.x*64 + w*16;
    int xrow = min(rowbase + m16, NPTS - 1);

    // A fragments (hi/lo truncation split) + s2 partial
    bf16x8 aH[4], aL[4];
    float s2p = 0.f;
    const float* xb = X + (size_t)xrow*DC + g4*8;
    const float* ib = wsf + WS_INVPSI_F + g4*8;
#pragma unroll
    for (int ks = 0; ks < 4; ks++) {
        float xs[8], is[8];
        *(float4*)&xs[0] = *(const float4*)(xb + ks*32);
        *(float4*)&xs[4] = *(const float4*)(xb + ks*32 + 4);
        *(float4*)&is[0] = *(const float4*)(ib + ks*32);
        *(float4*)&is[4] = *(const float4*)(ib + ks*32 + 4);
#pragma unroll
        for (int j = 0; j < 8; j++) {
            float hf;
            aH[ks][j] = bfhi(xs[j], &hf);
            aL[ks][j] = bftrunc(xs[j] - hf);
            s2p = fmaf(xs[j]*is[j], xs[j], s2p);
        }
    }
    s2p += __shfl_xor(s2p, 16, 64);
    s2p += __shfl_xor(s2p, 32, 64);

    __syncthreads();

    f32x4 acc[5];
#pragma unroll
    for (int i = 0; i < 5; i++) acc[i] = (f32x4){0.f, 0.f, 0.f, 0.f};
#pragma unroll
    for (int nt = 0; nt < 5; nt++) {
        int row = (nt < 4 ? nt*16 : 64) + m16;
        unsigned rb = (unsigned)row << 8;
        unsigned sw = (unsigned)(row & 7) << 4;
#pragma unroll
        for (int ks = 0; ks < 4; ks++) {
            unsigned bo = (rb + (unsigned)((ks*32 + g4*8)*2)) ^ sw;
            bf16x8 bh = *(const bf16x8*)(lds + bo);
            bf16x8 bl = *(const bf16x8*)(lds + LDS_H_BYTES + bo);
            acc[nt] = __builtin_amdgcn_mfma_f32_16x16x32_bf16(aH[ks], bh, acc[nt], 0, 0, 0);
            acc[nt] = __builtin_amdgcn_mfma_f32_16x16x32_bf16(aL[ks], bh, acc[nt], 0, 0, 0);
            acc[nt] = __builtin_amdgcn_mfma_f32_16x16x32_bf16(aH[ks], bl, acc[nt], 0, 0, 0);
        }
    }

#pragma unroll
    for (int nt = 0; nt < 4; nt++) {
        float c2v = wsf[WS_C2P_F + yb*4 + nt];
#pragma unroll
        for (int j = 0; j < 4; j++) {
            float v = acc[nt][j]*acc[nt][j];
            v += __shfl_xor(v, 1, 64);
            v += __shfl_xor(v, 2, 64);
            v += __shfl_xor(v, 4, 64);
            v += __shfl_xor(v, 8, 64);                 // sum over q for row g4*4+j
            float pv  = __shfl(acc[4][j], (l & 48) | nt, 64);
            float s2j = __shfl(s2p, (l & 48) | (g4*4 + j), 64);
            float lr = c2v + pv - 0.5f*s2j + 0.5f*v;
            int row = rowbase + g4*4 + j;
            if (m16 == 0 && row < NPTS)
                out[(size_t)row*KC + yb*4 + nt] = lr;
        }
    }
}

// ---------------------------------------------------------------------------
// Kernel 3: in-place logsumexp normalize + log-likelihood output.
// ---------------------------------------------------------------------------
__global__ __launch_bounds__(256) void mfa_norm(float* __restrict__ out)
{
    int n = blockIdx.x * 256 + threadIdx.x;
    if (n >= NPTS) return;
    float lr[KC];
#pragma unroll
    for (int i = 0; i < 8; i++)
        *(float4*)&lr[i*4] = *(const float4*)(out + (size_t)n*KC + i*4);
    float m = -1e30f;
#pragma unroll
    for (int k = 0; k < KC; k++) m = fmaxf(m, lr[k]);
    float s = 0.0f;
#pragma unroll
    for (int k = 0; k < KC; k++) s += expf(lr[k] - m);
    float ll = m + logf(s);
#pragma unroll
    for (int k = 0; k < KC; k++) lr[k] -= ll;
#pragma unroll
    for (int i = 0; i < 8; i++)
        *(float4*)(out + (size_t)n*KC + i*4) = *(const float4*)&lr[i*4];
    out[(size_t)NPTS*KC + n] = ll;
}

extern "C" void kernel_launch(void* const* d_in, const int* in_sizes, int n_in,
                              void* d_out, int out_size, void* d_ws, size_t ws_size,
                              hipStream_t stream)
{
    const float* X       = (const float*)d_in[0];
    const float* log_pi  = (const float*)d_in[1];
    const float* mu      = (const float*)d_in[2];
    const float* Lam     = (const float*)d_in[3];
    const float* log_psi = (const float*)d_in[4];
    float* out = (float*)d_out;
    float* wsf = (float*)d_ws;
    short* btH = (short*)((char*)d_ws + WS_BTHI_B);
    short* btL = (short*)((char*)d_ws + WS_BTLO_B);

    hipLaunchKernelGGL(mfa_pre, dim3(KC), dim3(256), 0, stream,
                       log_pi, mu, Lam, log_psi, wsf, btH, btL);
    hipLaunchKernelGGL(mfa_gemm, dim3(313, 8), dim3(256), 0, stream,
                       X, wsf, btH, btL, out);
    hipLaunchKernelGGL(mfa_norm, dim3(79), dim3(256), 0, stream, out);
}